// Round 1
// baseline (36288.724 us; speedup 1.0000x reference)
//
#include <hip/hip_runtime.h>

// Stacked Clockwork RNN, MI355X baseline (round 1: correctness-first).
// B=32, T=512, DIN=H=1024, DEPTH=4, groups of 256 cols with periods 1,2,4,8.
// One kernel launch per (t, depth): 2048 launches in the graph.

#define BB 32
#define TT 512
#define HH 1024
#define OUT_BSTRIDE (TT * 4 * HH)   // out[b][t][d][c]: b-stride

__device__ __forceinline__ void accum_part(float (&acc)[8][4],
    const float* __restrict__ W, int c0,
    const float* __restrict__ in, int in_bstride, int b0,
    int kbase, int len)
{
#pragma unroll 4
  for (int kk = 0; kk < len; kk += 4) {
    const int k = kbase + kk;
    const float4 w0 = *(const float4*)(W + (size_t)(k + 0) * HH + c0);
    const float4 w1 = *(const float4*)(W + (size_t)(k + 1) * HH + c0);
    const float4 w2 = *(const float4*)(W + (size_t)(k + 2) * HH + c0);
    const float4 w3 = *(const float4*)(W + (size_t)(k + 3) * HH + c0);
#pragma unroll
    for (int bb = 0; bb < 8; ++bb) {
      const float4 v = *(const float4*)(in + (size_t)(b0 + bb) * (size_t)in_bstride + k);
      acc[bb][0] = fmaf(v.w, w3.x, fmaf(v.z, w2.x, fmaf(v.y, w1.x, fmaf(v.x, w0.x, acc[bb][0]))));
      acc[bb][1] = fmaf(v.w, w3.y, fmaf(v.z, w2.y, fmaf(v.y, w1.y, fmaf(v.x, w0.y, acc[bb][1]))));
      acc[bb][2] = fmaf(v.w, w3.z, fmaf(v.z, w2.z, fmaf(v.y, w1.z, fmaf(v.x, w0.z, acc[bb][2]))));
      acc[bb][3] = fmaf(v.w, w3.w, fmaf(v.z, w2.w, fmaf(v.y, w1.w, fmaf(v.x, w0.w, acc[bb][3]))));
    }
  }
}

// Block = 4 output columns (all in one clock group). Threads: 4 b-groups x 64 k-slices.
__global__ __launch_bounds__(256) void cw_step(
    int t1,                                  // 1-based timestep
    const float* __restrict__ cur_base,      // depth input: x slice (d=0) or cur buffer
    int cur_bstride,
    float* __restrict__ cur_out,             // next depth's cur (null for d=3)
    const float* __restrict__ h_read_d,      // [B][H] state slice (t-1)
    float* __restrict__ h_write_d,           // [B][H] state slice (t)
    const float* __restrict__ wx,            // [1024][1024]
    const float* __restrict__ wh,            // [1024][1024] (depth slice)
    const float* __restrict__ bias_d,        // [1024]
    float* __restrict__ out_td)              // out + ((t-1)*4 + d)*H
{
  const int cb = blockIdx.x;
  const int c0 = cb << 2;        // first of 4 columns
  const int g  = c0 >> 8;        // clock group 0..3, period 2^g
  const int tid = threadIdx.x;

  // inactive group this step: copy state through
  if ((t1 & ((1 << g) - 1)) != 0) {
    if (tid < 128) {
      const int b = tid >> 2;
      const int c = c0 + (tid & 3);
      const float v = h_read_d[b * HH + c];
      h_write_d[b * HH + c] = v;
      out_td[(size_t)b * OUT_BSTRIDE + c] = v;
      if (cur_out) cur_out[b * HH + c] = v;
    }
    return;
  }

  const int ks = tid & 63;         // k-slice 0..63
  const int b0 = (tid >> 6) << 3;  // batch group base: 0,8,16,24

  float acc[8][4] = {};

  // x/cur contribution: full 1024 reduction
  accum_part(acc, wx, c0, cur_base, cur_bstride, b0, ks * 16, 16);

  // recurrent contribution: CW mask => sources j in [256g, 1024)
  const int j0  = g << 8;
  const int len = (HH - j0) >> 6;  // 16,12,8,4 (all multiples of 4)
  accum_part(acc, wh, c0, h_read_d, HH, b0, j0 + ks * len, len);

  // reduce 64 k-slice partials per (b, c) via LDS
  __shared__ float red[64][129];   // pad 129: writes stride 129 -> conflict-free
#pragma unroll
  for (int bb = 0; bb < 8; ++bb)
#pragma unroll
    for (int c = 0; c < 4; ++c)
      red[ks][(b0 + bb) * 4 + c] = acc[bb][c];
  __syncthreads();

  if (tid < 128) {
    const int b = tid >> 2;
    const int c = tid & 3;
    float s = bias_d[c0 + c];
#pragma unroll 8
    for (int i = 0; i < 64; ++i) s += red[i][b * 4 + c];
    const float v = tanhf(s);
    h_write_d[b * HH + c0 + c] = v;
    out_td[(size_t)b * OUT_BSTRIDE + c0 + c] = v;
    if (cur_out) cur_out[b * HH + c0 + c] = v;
  }
}

extern "C" void kernel_launch(void* const* d_in, const int* in_sizes, int n_in,
                              void* d_out, int out_size, void* d_ws, size_t ws_size,
                              hipStream_t stream) {
  const float* x    = (const float*)d_in[0];  // [B][T][DIN]
  const float* Wx0  = (const float*)d_in[1];  // [DIN][H]
  const float* Wxd  = (const float*)d_in[2];  // [3][H][H]
  const float* Wh   = (const float*)d_in[3];  // [4][H][H]
  const float* bias = (const float*)d_in[4];  // [4][H]
  // d_in[5] = periods, hardcoded as groups of 256 with periods 1,2,4,8
  float* out = (float*)d_out;                 // [B][T][4][H]
  float* ws  = (float*)d_ws;

  float* hA = ws;                  // [4][B][H] state ping
  float* hB = hA + 4 * BB * HH;    // [4][B][H] state pong
  float* cA = hB + 4 * BB * HH;    // [B][H] cur ping
  float* cB = cA + BB * HH;        // [B][H] cur pong

  // h0 = 0 (ws is poisoned before every call)
  hipMemsetAsync(hA, 0, sizeof(float) * 4 * BB * HH, stream);

  for (int t1 = 1; t1 <= TT; ++t1) {
    float* hr = (t1 & 1) ? hA : hB;
    float* hw = (t1 & 1) ? hB : hA;
    for (int d = 0; d < 4; ++d) {
      const float* cur_base = (d == 0) ? (x + (size_t)(t1 - 1) * HH)
                                       : ((d & 1) ? cA : cB);
      const int cstride = (d == 0) ? (TT * HH) : HH;
      float* cur_out = (d == 3) ? nullptr : ((d & 1) ? cB : cA);
      const float* wx = (d == 0) ? Wx0 : (Wxd + (size_t)(d - 1) * HH * HH);
      const float* wh = Wh + (size_t)d * HH * HH;
      cw_step<<<256, 256, 0, stream>>>(
          t1, cur_base, cstride, cur_out,
          hr + (size_t)d * BB * HH, hw + (size_t)d * BB * HH,
          wx, wh, bias + (size_t)d * HH,
          out + ((size_t)(t1 - 1) * 4 + d) * HH);
    }
  }
}